// Round 4
// baseline (329.348 us; speedup 1.0000x reference)
//
#include <hip/hip_runtime.h>
#include <hip/hip_bf16.h>

#define N_NODES 50000
#define NP1     50001
#define N_EDGES 800000
#define NFEAT   256
#define NHID    64
#define HEADS   4
#define NCLASS  16
#define NEG_SLOPE 0.2f

typedef __attribute__((ext_vector_type(8))) short short8;
typedef __attribute__((ext_vector_type(4))) float floatx4;

__device__ __forceinline__ float blo(unsigned int u) { return __uint_as_float(u << 16); }
__device__ __forceinline__ float bhi(unsigned int u) { return __uint_as_float(u & 0xffff0000u); }
__device__ __forceinline__ unsigned short f2b(float f) {
    unsigned int x = __float_as_uint(f);
    unsigned int r = x + 0x7fffu + ((x >> 16) & 1u);
    return (unsigned short)(r >> 16);
}
__device__ __forceinline__ unsigned int pack2(float a, float b) {
    return (unsigned int)f2b(a) | ((unsigned int)f2b(b) << 16);
}
__device__ __forceinline__ float leaky(float x) { return fmaxf(x, NEG_SLOPE * x); }

// ---------------- fused weight prep ----------------
// blocks 0..255: W1E row b (transpose of W1 col b) -> bf16
// block 256: W2T transpose + Wel/Wer fold (rows 256..263) + zero pad (264..271)
__global__ void prep_kernel(const float* __restrict__ W1, const float* __restrict__ W2,
                            const float* __restrict__ al1, const float* __restrict__ ar1,
                            unsigned short* __restrict__ W1E, unsigned short* __restrict__ W2T) {
    int b = blockIdx.x, t = threadIdx.x;
    if (b < 256) {
        W1E[b * 256 + t] = f2b(W1[t * 256 + b]);
    } else {
        int n = t >> 4, k0 = (t & 15) * 16;
#pragma unroll
        for (int j = 0; j < 16; ++j)
            W2T[n * 256 + k0 + j] = f2b(W2[(k0 + j) * 16 + n]);
        // Wel/Wer: thread k = t, heads 0..3
#pragma unroll
        for (int h = 0; h < 4; ++h) {
            float sl = 0.f, sr = 0.f;
            for (int d = 0; d < 64; ++d) {
                float w = W1[t * 256 + h * 64 + d];
                sl = fmaf(w, al1[h * 64 + d], sl);
                sr = fmaf(w, ar1[h * 64 + d], sr);
            }
            W1E[(256 + h) * 256 + t] = f2b(sl);
            W1E[(260 + h) * 256 + t] = f2b(sr);
        }
#pragma unroll
        for (int r = 264; r < 272; ++r) W1E[r * 256 + t] = 0;
    }
}

// ---------------- CSR build ----------------
__global__ void hist_kernel(const int* __restrict__ dst, int* __restrict__ cnt) {
    int e = blockIdx.x * blockDim.x + threadIdx.x;
    if (e < N_EDGES) atomicAdd(&cnt[dst[e]], 1);
}

__global__ __launch_bounds__(256) void scan1_kernel(const int* __restrict__ cnt,
                                                    int* __restrict__ partial,
                                                    int* __restrict__ bsum) {
    __shared__ int wsum[4];
    int t = threadIdx.x;
    int base = blockIdx.x * 1024 + t * 4;
    int v0 = (base + 0 < N_NODES) ? cnt[base + 0] : 0;
    int v1 = (base + 1 < N_NODES) ? cnt[base + 1] : 0;
    int v2 = (base + 2 < N_NODES) ? cnt[base + 2] : 0;
    int v3 = (base + 3 < N_NODES) ? cnt[base + 3] : 0;
    int s = v0 + v1 + v2 + v3;
    int lane = t & 63, w = t >> 6;
    int incl = s;
#pragma unroll
    for (int off = 1; off < 64; off <<= 1) {
        int x = __shfl_up(incl, off);
        if (lane >= off) incl += x;
    }
    if (lane == 63) wsum[w] = incl;
    __syncthreads();
    int woff = 0;
    for (int k = 0; k < w; ++k) woff += wsum[k];
    int excl = woff + incl - s;
    if (base + 0 < NP1) partial[base + 0] = excl;
    if (base + 1 < NP1) partial[base + 1] = excl + v0;
    if (base + 2 < NP1) partial[base + 2] = excl + v0 + v1;
    if (base + 3 < NP1) partial[base + 3] = excl + v0 + v1 + v2;
    if (t == 255) bsum[blockIdx.x] = woff + incl;
}

__global__ void scan2_kernel(const int* __restrict__ bsum, int* __restrict__ boff) {
    int t = threadIdx.x;
    int v = (t < 49) ? bsum[t] : 0;
    int incl = v;
#pragma unroll
    for (int off = 1; off < 64; off <<= 1) {
        int x = __shfl_up(incl, off);
        if (t >= off) incl += x;
    }
    if (t < 49) boff[t] = incl - v;
}

__global__ void scan3_kernel(const int* __restrict__ partial, const int* __restrict__ boff,
                             int* __restrict__ row_ptr, int* __restrict__ fill) {
    int i = blockIdx.x * 256 + threadIdx.x;
    if (i < NP1) {
        int v = partial[i] + boff[i >> 10];
        row_ptr[i] = v;
        if (i < N_NODES) fill[i] = v;
    }
}

__global__ void scatter_kernel(const int* __restrict__ src, const int* __restrict__ dst,
                               int* __restrict__ fill, int* __restrict__ csr_src) {
    int e = blockIdx.x * blockDim.x + threadIdx.x;
    if (e < N_EDGES) {
        int pos = atomicAdd(&fill[dst[e]], 1);
        csr_src[pos] = src[e];
    }
}

// ---------------- GEMM1 (bf16 MFMA): [feat1 | el | er] = x @ [W1 | Wel | Wer] ----------------
// tile 128(M) x 272(N=256 feat + 8 attn + 8 pad), BK=32
__global__ __launch_bounds__(256, 2) void gemm1_mfma_kernel(
        const float* __restrict__ X, const unsigned short* __restrict__ BT,
        unsigned short* __restrict__ C, float* __restrict__ el, float* __restrict__ er) {
    __shared__ __align__(16) unsigned short As[128 * 40];
    __shared__ __align__(16) unsigned short Bs[272 * 40];
    int t = threadIdx.x;
    int m0 = blockIdx.x * 128;
    int lane = t & 63, wm = t >> 6;
    int quad = lane >> 4, l16 = lane & 15;

    floatx4 acc[2][17];
#pragma unroll
    for (int i = 0; i < 2; ++i)
#pragma unroll
        for (int j = 0; j < 17; ++j) acc[i][j] = (floatx4){0.f, 0.f, 0.f, 0.f};

    int arow = t >> 1, ak = (t & 1) * 16;
    int grow = m0 + arow;
    const float* xrow = X + (size_t)grow * 256 + ak;

    for (int k0 = 0; k0 < 256; k0 += 32) {
        // stage A: fp32 -> bf16, 16 elems/thread
        float4 v0 = make_float4(0.f, 0.f, 0.f, 0.f), v1 = v0, v2 = v0, v3 = v0;
        if (grow < N_NODES) {
            v0 = *(const float4*)(xrow + k0 + 0);
            v1 = *(const float4*)(xrow + k0 + 4);
            v2 = *(const float4*)(xrow + k0 + 8);
            v3 = *(const float4*)(xrow + k0 + 12);
        }
        uint4 p0, p1;
        p0.x = pack2(v0.x, v0.y); p0.y = pack2(v0.z, v0.w);
        p0.z = pack2(v1.x, v1.y); p0.w = pack2(v1.z, v1.w);
        p1.x = pack2(v2.x, v2.y); p1.y = pack2(v2.z, v2.w);
        p1.z = pack2(v3.x, v3.y); p1.w = pack2(v3.z, v3.w);
        *(uint4*)&As[arow * 40 + ak] = p0;
        *(uint4*)&As[arow * 40 + ak + 8] = p1;
        // stage B: 272 rows x 32 k = 1088 16B-chunks
#pragma unroll
        for (int i = 0; i < 5; ++i) {
            int ch = t + i * 256;
            if (ch < 1088) {
                int row = ch >> 2, off = (ch & 3) * 8;
                *(uint4*)&Bs[row * 40 + off] = *(const uint4*)(BT + row * 256 + k0 + off);
            }
        }
        __syncthreads();

        short8 a0 = *(const short8*)&As[(wm * 32 + l16) * 40 + quad * 8];
        short8 a1 = *(const short8*)&As[(wm * 32 + 16 + l16) * 40 + quad * 8];
#pragma unroll
        for (int nf = 0; nf < 17; ++nf) {
            short8 bb = *(const short8*)&Bs[(nf * 16 + l16) * 40 + quad * 8];
            acc[0][nf] = __builtin_amdgcn_mfma_f32_16x16x32_bf16(a0, bb, acc[0][nf], 0, 0, 0);
            acc[1][nf] = __builtin_amdgcn_mfma_f32_16x16x32_bf16(a1, bb, acc[1][nf], 0, 0, 0);
        }
        __syncthreads();
    }

    // el/er from frag 16: local col l16 -> global col 256+l16
#pragma unroll
    for (int mf = 0; mf < 2; ++mf) {
#pragma unroll
        for (int r = 0; r < 4; ++r) {
            int row = m0 + wm * 32 + mf * 16 + quad * 4 + r;
            if (row < N_NODES && l16 < 8) {
                float v = acc[mf][16][r];
                if (l16 < 4) el[row * 4 + l16] = v;
                else er[row * 4 + (l16 - 4)] = v;
            }
        }
    }

    // feat frags 0..15: per-wave LDS transpose, wide coalesced stores
    unsigned short* scr = Bs + wm * 1536;  // double-buffered: (p&1)*768
    int half = lane >> 5, l32 = lane & 31;
    int rrow = l32 >> 1, coff = (l32 & 1) * 8;
#pragma unroll
    for (int mf = 0; mf < 2; ++mf) {
#pragma unroll
        for (int p = 0; p < 8; ++p) {
            unsigned short* base = scr + (p & 1) * 768;
#pragma unroll
            for (int fr = 0; fr < 2; ++fr) {
                int nf = 2 * p + fr;
                unsigned short* fb = base + fr * 384;
#pragma unroll
                for (int r = 0; r < 4; ++r)
                    fb[(quad * 4 + r) * 24 + l16] = f2b(acc[mf][nf][r]);
            }
            uint4 val = *(const uint4*)(base + half * 384 + rrow * 24 + coff);
            int row = m0 + wm * 32 + mf * 16 + rrow;
            int nf = 2 * p + half;
            if (row < N_NODES)
                *(uint4*)&C[(size_t)row * 256 + nf * 16 + coff] = val;
        }
    }
}

// ---------------- layer-1 aggregation: quarter-wave per edge, 4 in flight ----------------
__global__ void agg1_kernel(const unsigned short* __restrict__ feat1,
                            const float* __restrict__ el, const float* __restrict__ er,
                            const int* __restrict__ row_ptr, const int* __restrict__ csr_src,
                            const float* __restrict__ b1, unsigned short* __restrict__ h1b) {
    int wave = threadIdx.x >> 6, lane = threadIdx.x & 63;
    int n = blockIdx.x * 4 + wave;
    if (n >= N_NODES) return;
    int q = lane >> 4, l16 = lane & 15;
    int h = l16 >> 2;  // head of dims l16*16..+15
    float er_h = er[n * 4 + h];
    int start = row_ptr[n], end = row_ptr[n + 1];

    float acc[16];
#pragma unroll
    for (int j = 0; j < 16; ++j) acc[j] = 0.f;
    float denom = 0.f;

    for (int i = start + q; i < end; i += 4) {
        int s = csr_src[i];
        float ex = __expf(leaky(el[s * 4 + h] + er_h));
        const uint4* p = (const uint4*)(feat1 + (size_t)s * 256 + l16 * 16);
        uint4 u0 = p[0];
        uint4 u1 = p[1];
        denom += ex;
        acc[0]  = fmaf(blo(u0.x), ex, acc[0]);
        acc[1]  = fmaf(bhi(u0.x), ex, acc[1]);
        acc[2]  = fmaf(blo(u0.y), ex, acc[2]);
        acc[3]  = fmaf(bhi(u0.y), ex, acc[3]);
        acc[4]  = fmaf(blo(u0.z), ex, acc[4]);
        acc[5]  = fmaf(bhi(u0.z), ex, acc[5]);
        acc[6]  = fmaf(blo(u0.w), ex, acc[6]);
        acc[7]  = fmaf(bhi(u0.w), ex, acc[7]);
        acc[8]  = fmaf(blo(u1.x), ex, acc[8]);
        acc[9]  = fmaf(bhi(u1.x), ex, acc[9]);
        acc[10] = fmaf(blo(u1.y), ex, acc[10]);
        acc[11] = fmaf(bhi(u1.y), ex, acc[11]);
        acc[12] = fmaf(blo(u1.z), ex, acc[12]);
        acc[13] = fmaf(bhi(u1.z), ex, acc[13]);
        acc[14] = fmaf(blo(u1.w), ex, acc[14]);
        acc[15] = fmaf(bhi(u1.w), ex, acc[15]);
    }
    // combine the 4 quarter-streams
#pragma unroll
    for (int j = 0; j < 16; ++j) {
        acc[j] += __shfl_xor(acc[j], 16);
        acc[j] += __shfl_xor(acc[j], 32);
    }
    denom += __shfl_xor(denom, 16);
    denom += __shfl_xor(denom, 32);

    if (q == 0) {
        float inv = (end > start) ? 1.f / denom : 0.f;
        float o[16];
#pragma unroll
        for (int j = 0; j < 16; j += 4) {
            float4 b4 = *(const float4*)&b1[l16 * 16 + j];
            o[j + 0] = fmaf(acc[j + 0], inv, b4.x);
            o[j + 1] = fmaf(acc[j + 1], inv, b4.y);
            o[j + 2] = fmaf(acc[j + 2], inv, b4.z);
            o[j + 3] = fmaf(acc[j + 3], inv, b4.w);
        }
#pragma unroll
        for (int j = 0; j < 16; ++j) o[j] = o[j] > 0.f ? o[j] : __expf(o[j]) - 1.f;
        uint4 pa, pb;
        pa.x = pack2(o[0], o[1]);   pa.y = pack2(o[2], o[3]);
        pa.z = pack2(o[4], o[5]);   pa.w = pack2(o[6], o[7]);
        pb.x = pack2(o[8], o[9]);   pb.y = pack2(o[10], o[11]);
        pb.z = pack2(o[12], o[13]); pb.w = pack2(o[14], o[15]);
        uint4* dst = (uint4*)(h1b + (size_t)n * 256 + l16 * 16);
        dst[0] = pa;
        dst[1] = pb;
    }
}

// ---------------- GEMM2 (bf16 MFMA, no LDS) + fused el2/er2 ----------------
__global__ __launch_bounds__(256) void gemm2_mfma_kernel(
        const unsigned short* __restrict__ h1b, const unsigned short* __restrict__ W2T,
        const float* __restrict__ al2, const float* __restrict__ ar2,
        float* __restrict__ feat2, float* __restrict__ el2, float* __restrict__ er2) {
    int wave = threadIdx.x >> 6, lane = threadIdx.x & 63;
    int l16 = lane & 15, quad = lane >> 4;
    int row0 = (blockIdx.x * 4 + wave) * 16;
    if (row0 >= N_NODES) return;
    floatx4 acc = (floatx4){0.f, 0.f, 0.f, 0.f};
    const unsigned short* arow = h1b + (size_t)(row0 + l16) * 256 + quad * 8;
    const unsigned short* brow = W2T + (size_t)l16 * 256 + quad * 8;
#pragma unroll
    for (int k0 = 0; k0 < 256; k0 += 32) {
        short8 a = *(const short8*)(arow + k0);
        short8 b = *(const short8*)(brow + k0);
        acc = __builtin_amdgcn_mfma_f32_16x16x32_bf16(a, b, acc, 0, 0, 0);
    }
    float a2 = al2[l16], r2 = ar2[l16];
#pragma unroll
    for (int r = 0; r < 4; ++r) {
        int row = row0 + quad * 4 + r;
        float v = acc[r];
        feat2[row * 16 + l16] = v;
        float pl = v * a2, pr = v * r2;
#pragma unroll
        for (int off = 1; off < 16; off <<= 1) {
            pl += __shfl_xor(pl, off);
            pr += __shfl_xor(pr, off);
        }
        if (l16 == 0) {
            el2[row] = pl;
            er2[row] = pr;
        }
    }
}

// ---------------- layer-2 aggregation + log_softmax ----------------
__global__ void agg2_kernel(const float* __restrict__ feat2, const float* __restrict__ el2,
                            const float* __restrict__ er2, const int* __restrict__ row_ptr,
                            const int* __restrict__ csr_src, const float* __restrict__ b2,
                            float* __restrict__ out) {
    int wave = threadIdx.x >> 6, lane = threadIdx.x & 63;
    int n = blockIdx.x * 4 + wave;
    if (n >= N_NODES) return;
    int start = row_ptr[n], end = row_ptr[n + 1];
    float ern = er2[n];
    int eo = lane >> 4, c = lane & 15;
    float acc = 0.f, denom = 0.f;
    for (int i = start + eo; i < end; i += 4) {
        int s = csr_src[i];
        float ex = __expf(leaky(el2[s] + ern));
        denom += ex;
        acc = fmaf(feat2[s * 16 + c], ex, acc);
    }
    acc += __shfl_xor(acc, 16);
    acc += __shfl_xor(acc, 32);
    denom += __shfl_xor(denom, 16);
    denom += __shfl_xor(denom, 32);
    float v = ((end > start) ? acc / denom : 0.f) + b2[c];
    float mx = v;
#pragma unroll
    for (int off = 1; off < 16; off <<= 1) mx = fmaxf(mx, __shfl_xor(mx, off));
    float ex2 = __expf(v - mx);
    float s2 = ex2;
#pragma unroll
    for (int off = 1; off < 16; off <<= 1) s2 += __shfl_xor(s2, off);
    float res = v - mx - logf(s2);
    if (lane < 16) out[n * 16 + lane] = res;
}

// ---------------- launch ----------------
extern "C" void kernel_launch(void* const* d_in, const int* in_sizes, int n_in,
                              void* d_out, int out_size, void* d_ws, size_t ws_size,
                              hipStream_t stream) {
    const float* x   = (const float*)d_in[0];
    const int*   src = (const int*)d_in[1];
    const int*   dst = (const int*)d_in[2];
    const float* W1  = (const float*)d_in[3];
    const float* al1 = (const float*)d_in[4];
    const float* ar1 = (const float*)d_in[5];
    const float* b1  = (const float*)d_in[6];
    const float* W2  = (const float*)d_in[7];
    const float* al2 = (const float*)d_in[8];
    const float* ar2 = (const float*)d_in[9];
    const float* b2  = (const float*)d_in[10];
    float* out = (float*)d_out;

    char* ws = (char*)d_ws;
    size_t off = 0;
    auto alloc = [&](size_t bytes) -> void* {
        void* p = ws + off;
        off += (bytes + 255) & ~(size_t)255;
        return p;
    };
    unsigned short* W1E   = (unsigned short*)alloc((size_t)272 * 256 * 2);
    unsigned short* W2T   = (unsigned short*)alloc((size_t)16 * 256 * 2);
    unsigned short* feat1 = (unsigned short*)alloc((size_t)N_NODES * 256 * 2);
    unsigned short* h1b   = (unsigned short*)alloc((size_t)N_NODES * 256 * 2);
    float* feat2   = (float*)alloc((size_t)N_NODES * 16 * 4);
    float* el1     = (float*)alloc((size_t)N_NODES * 4 * 4);
    float* er1     = (float*)alloc((size_t)N_NODES * 4 * 4);
    float* el2     = (float*)alloc((size_t)N_NODES * 4);
    float* er2     = (float*)alloc((size_t)N_NODES * 4);
    int*   cnt     = (int*)alloc((size_t)N_NODES * 4);
    int*   fill    = (int*)alloc((size_t)N_NODES * 4);
    int*   row_ptr = (int*)alloc((size_t)NP1 * 4);
    int*   partial = (int*)alloc((size_t)NP1 * 4);
    int*   bsum    = (int*)alloc((size_t)64 * 4);
    int*   boff    = (int*)alloc((size_t)64 * 4);
    int*   csr_src = (int*)alloc((size_t)N_EDGES * 4);

    hipMemsetAsync(cnt, 0, (size_t)N_NODES * 4, stream);

    dim3 b256(256);
    prep_kernel<<<257, b256, 0, stream>>>(W1, W2, al1, ar1, W1E, W2T);
    // CSR build
    hist_kernel<<<(N_EDGES + 255) / 256, b256, 0, stream>>>(dst, cnt);
    scan1_kernel<<<49, b256, 0, stream>>>(cnt, partial, bsum);
    scan2_kernel<<<1, 64, 0, stream>>>(bsum, boff);
    scan3_kernel<<<(NP1 + 255) / 256, b256, 0, stream>>>(partial, boff, row_ptr, fill);
    scatter_kernel<<<(N_EDGES + 255) / 256, b256, 0, stream>>>(src, dst, fill, csr_src);

    // layer 1
    gemm1_mfma_kernel<<<(N_NODES + 127) / 128, b256, 0, stream>>>(x, W1E, feat1, el1, er1);
    agg1_kernel<<<(N_NODES + 3) / 4, b256, 0, stream>>>(feat1, el1, er1, row_ptr, csr_src, b1, h1b);

    // layer 2
    gemm2_mfma_kernel<<<(N_NODES + 63) / 64, b256, 0, stream>>>(h1b, W2T, al2, ar2, feat2, el2, er2);
    agg2_kernel<<<(N_NODES + 3) / 4, b256, 0, stream>>>(feat2, el2, er2, row_ptr, csr_src, b2, out);
}

// Round 5
// 324.443 us; speedup vs baseline: 1.0151x; 1.0151x over previous
//
#include <hip/hip_runtime.h>
#include <hip/hip_bf16.h>

#define N_NODES 50000
#define NP1     50001
#define N_EDGES 800000
#define NFEAT   256
#define NHID    64
#define HEADS   4
#define NCLASS  16
#define NEG_SLOPE 0.2f

typedef __attribute__((ext_vector_type(8))) short short8;
typedef __attribute__((ext_vector_type(4))) float floatx4;

__device__ __forceinline__ float blo(unsigned int u) { return __uint_as_float(u << 16); }
__device__ __forceinline__ float bhi(unsigned int u) { return __uint_as_float(u & 0xffff0000u); }
__device__ __forceinline__ unsigned short f2b(float f) {
    unsigned int x = __float_as_uint(f);
    unsigned int r = x + 0x7fffu + ((x >> 16) & 1u);
    return (unsigned short)(r >> 16);
}
__device__ __forceinline__ unsigned int pack2(float a, float b) {
    return (unsigned int)f2b(a) | ((unsigned int)f2b(b) << 16);
}
__device__ __forceinline__ float leaky(float x) { return fmaxf(x, NEG_SLOPE * x); }

// ---------------- fused weight prep ----------------
__global__ void prep_kernel(const float* __restrict__ W1, const float* __restrict__ W2,
                            const float* __restrict__ al1, const float* __restrict__ ar1,
                            unsigned short* __restrict__ W1E, unsigned short* __restrict__ W2T) {
    int b = blockIdx.x, t = threadIdx.x;
    if (b < 256) {
        W1E[b * 256 + t] = f2b(W1[t * 256 + b]);
    } else {
        int n = t >> 4, k0 = (t & 15) * 16;
#pragma unroll
        for (int j = 0; j < 16; ++j)
            W2T[n * 256 + k0 + j] = f2b(W2[(k0 + j) * 16 + n]);
#pragma unroll
        for (int h = 0; h < 4; ++h) {
            float sl = 0.f, sr = 0.f;
            for (int d = 0; d < 64; ++d) {
                float w = W1[t * 256 + h * 64 + d];
                sl = fmaf(w, al1[h * 64 + d], sl);
                sr = fmaf(w, ar1[h * 64 + d], sr);
            }
            W1E[(256 + h) * 256 + t] = f2b(sl);
            W1E[(260 + h) * 256 + t] = f2b(sr);
        }
#pragma unroll
        for (int r = 264; r < 272; ++r) W1E[r * 256 + t] = 0;
    }
}

// ---------------- CSR build ----------------
__global__ void hist_kernel(const int* __restrict__ dst, int* __restrict__ cnt) {
    int e = (blockIdx.x * blockDim.x + threadIdx.x) * 4;
    if (e < N_EDGES) {
        int4 d = *(const int4*)&dst[e];
        atomicAdd(&cnt[d.x], 1);
        atomicAdd(&cnt[d.y], 1);
        atomicAdd(&cnt[d.z], 1);
        atomicAdd(&cnt[d.w], 1);
    }
}

__global__ __launch_bounds__(256) void scan1_kernel(const int* __restrict__ cnt,
                                                    int* __restrict__ partial,
                                                    int* __restrict__ bsum) {
    __shared__ int wsum[4];
    int t = threadIdx.x;
    int base = blockIdx.x * 1024 + t * 4;
    int v0 = (base + 0 < N_NODES) ? cnt[base + 0] : 0;
    int v1 = (base + 1 < N_NODES) ? cnt[base + 1] : 0;
    int v2 = (base + 2 < N_NODES) ? cnt[base + 2] : 0;
    int v3 = (base + 3 < N_NODES) ? cnt[base + 3] : 0;
    int s = v0 + v1 + v2 + v3;
    int lane = t & 63, w = t >> 6;
    int incl = s;
#pragma unroll
    for (int off = 1; off < 64; off <<= 1) {
        int x = __shfl_up(incl, off);
        if (lane >= off) incl += x;
    }
    if (lane == 63) wsum[w] = incl;
    __syncthreads();
    int woff = 0;
    for (int k = 0; k < w; ++k) woff += wsum[k];
    int excl = woff + incl - s;
    if (base + 0 < NP1) partial[base + 0] = excl;
    if (base + 1 < NP1) partial[base + 1] = excl + v0;
    if (base + 2 < NP1) partial[base + 2] = excl + v0 + v1;
    if (base + 3 < NP1) partial[base + 3] = excl + v0 + v1 + v2;
    if (t == 255) bsum[blockIdx.x] = woff + incl;
}

// fused scan2+scan3: each block re-scans the 49 block sums, then applies
__global__ void scan3_kernel(const int* __restrict__ partial, const int* __restrict__ bsum,
                             int* __restrict__ row_ptr, int* __restrict__ fill) {
    __shared__ int sb[64];
    int t = threadIdx.x;
    if (t < 64) {
        int v = (t < 49) ? bsum[t] : 0;
        int incl = v;
#pragma unroll
        for (int off = 1; off < 64; off <<= 1) {
            int x = __shfl_up(incl, off);
            if (t >= off) incl += x;
        }
        sb[t] = incl - v;
    }
    __syncthreads();
    int i = blockIdx.x * 256 + t;
    if (i < NP1) {
        int v = partial[i] + sb[i >> 10];
        row_ptr[i] = v;
        if (i < N_NODES) fill[i] = v;
    }
}

__global__ void scatter_kernel(const int* __restrict__ src, const int* __restrict__ dst,
                               int* __restrict__ fill, int* __restrict__ csr_src) {
    int e = (blockIdx.x * blockDim.x + threadIdx.x) * 4;
    if (e < N_EDGES) {
        int4 d = *(const int4*)&dst[e];
        int4 s = *(const int4*)&src[e];
        csr_src[atomicAdd(&fill[d.x], 1)] = s.x;
        csr_src[atomicAdd(&fill[d.y], 1)] = s.y;
        csr_src[atomicAdd(&fill[d.z], 1)] = s.z;
        csr_src[atomicAdd(&fill[d.w], 1)] = s.w;
    }
}

// ---------------- GEMM1 (bf16 MFMA): [feat1 | el | er] = x @ [W1 | Wel | Wer] ----------------
__global__ __launch_bounds__(256, 2) void gemm1_mfma_kernel(
        const float* __restrict__ X, const unsigned short* __restrict__ BT,
        unsigned short* __restrict__ C, float* __restrict__ el, float* __restrict__ er) {
    __shared__ __align__(16) unsigned short As[128 * 40];
    __shared__ __align__(16) unsigned short Bs[272 * 40];
    int t = threadIdx.x;
    int m0 = blockIdx.x * 128;
    int lane = t & 63, wm = t >> 6;
    int quad = lane >> 4, l16 = lane & 15;

    floatx4 acc[2][17];
#pragma unroll
    for (int i = 0; i < 2; ++i)
#pragma unroll
        for (int j = 0; j < 17; ++j) acc[i][j] = (floatx4){0.f, 0.f, 0.f, 0.f};

    int arow = t >> 1, ak = (t & 1) * 16;
    int grow = m0 + arow;
    const float* xrow = X + (size_t)grow * 256 + ak;

    for (int k0 = 0; k0 < 256; k0 += 32) {
        float4 v0 = make_float4(0.f, 0.f, 0.f, 0.f), v1 = v0, v2 = v0, v3 = v0;
        if (grow < N_NODES) {
            v0 = *(const float4*)(xrow + k0 + 0);
            v1 = *(const float4*)(xrow + k0 + 4);
            v2 = *(const float4*)(xrow + k0 + 8);
            v3 = *(const float4*)(xrow + k0 + 12);
        }
        uint4 p0, p1;
        p0.x = pack2(v0.x, v0.y); p0.y = pack2(v0.z, v0.w);
        p0.z = pack2(v1.x, v1.y); p0.w = pack2(v1.z, v1.w);
        p1.x = pack2(v2.x, v2.y); p1.y = pack2(v2.z, v2.w);
        p1.z = pack2(v3.x, v3.y); p1.w = pack2(v3.z, v3.w);
        *(uint4*)&As[arow * 40 + ak] = p0;
        *(uint4*)&As[arow * 40 + ak + 8] = p1;
#pragma unroll
        for (int i = 0; i < 5; ++i) {
            int ch = t + i * 256;
            if (ch < 1088) {
                int row = ch >> 2, off = (ch & 3) * 8;
                *(uint4*)&Bs[row * 40 + off] = *(const uint4*)(BT + row * 256 + k0 + off);
            }
        }
        __syncthreads();

        short8 a0 = *(const short8*)&As[(wm * 32 + l16) * 40 + quad * 8];
        short8 a1 = *(const short8*)&As[(wm * 32 + 16 + l16) * 40 + quad * 8];
#pragma unroll
        for (int nf = 0; nf < 17; ++nf) {
            short8 bb = *(const short8*)&Bs[(nf * 16 + l16) * 40 + quad * 8];
            acc[0][nf] = __builtin_amdgcn_mfma_f32_16x16x32_bf16(a0, bb, acc[0][nf], 0, 0, 0);
            acc[1][nf] = __builtin_amdgcn_mfma_f32_16x16x32_bf16(a1, bb, acc[1][nf], 0, 0, 0);
        }
        __syncthreads();
    }

#pragma unroll
    for (int mf = 0; mf < 2; ++mf) {
#pragma unroll
        for (int r = 0; r < 4; ++r) {
            int row = m0 + wm * 32 + mf * 16 + quad * 4 + r;
            if (row < N_NODES && l16 < 8) {
                float v = acc[mf][16][r];
                if (l16 < 4) el[row * 4 + l16] = v;
                else er[row * 4 + (l16 - 4)] = v;
            }
        }
    }

    unsigned short* scr = Bs + wm * 1536;
    int half = lane >> 5, l32 = lane & 31;
    int rrow = l32 >> 1, coff = (l32 & 1) * 8;
#pragma unroll
    for (int mf = 0; mf < 2; ++mf) {
#pragma unroll
        for (int p = 0; p < 8; ++p) {
            unsigned short* base = scr + (p & 1) * 768;
#pragma unroll
            for (int fr = 0; fr < 2; ++fr) {
                int nf = 2 * p + fr;
                unsigned short* fb = base + fr * 384;
#pragma unroll
                for (int r = 0; r < 4; ++r)
                    fb[(quad * 4 + r) * 24 + l16] = f2b(acc[mf][nf][r]);
            }
            uint4 val = *(const uint4*)(base + half * 384 + rrow * 24 + coff);
            int row = m0 + wm * 32 + mf * 16 + rrow;
            int nf = 2 * p + half;
            if (row < N_NODES)
                *(uint4*)&C[(size_t)row * 256 + nf * 16 + coff] = val;
        }
    }
}

// ---------------- layer-1 aggregation: quarter-wave per edge, 2x unroll (8 in flight) ----------------
__global__ void agg1_kernel(const unsigned short* __restrict__ feat1,
                            const float* __restrict__ el, const float* __restrict__ er,
                            const int* __restrict__ row_ptr, const int* __restrict__ csr_src,
                            const float* __restrict__ b1, unsigned short* __restrict__ h1b) {
    int wave = threadIdx.x >> 6, lane = threadIdx.x & 63;
    int n = blockIdx.x * 4 + wave;
    if (n >= N_NODES) return;
    int q = lane >> 4, l16 = lane & 15;
    int h = l16 >> 2;
    float er_h = er[n * 4 + h];
    int start = row_ptr[n], end = row_ptr[n + 1];

    float acc[16];
#pragma unroll
    for (int j = 0; j < 16; ++j) acc[j] = 0.f;
    float denom = 0.f;

    int i = start + q;
    for (; i + 4 < end; i += 8) {
        int s0 = csr_src[i];
        int s1 = csr_src[i + 4];
        float ex0 = __expf(leaky(el[s0 * 4 + h] + er_h));
        float ex1 = __expf(leaky(el[s1 * 4 + h] + er_h));
        const uint4* p0 = (const uint4*)(feat1 + (size_t)s0 * 256 + l16 * 16);
        const uint4* p1 = (const uint4*)(feat1 + (size_t)s1 * 256 + l16 * 16);
        uint4 a0 = p0[0], a1 = p0[1];
        uint4 b0 = p1[0], b1v = p1[1];
        denom += ex0 + ex1;
        acc[0]  = fmaf(blo(a0.x), ex0, acc[0]);   acc[0]  = fmaf(blo(b0.x), ex1, acc[0]);
        acc[1]  = fmaf(bhi(a0.x), ex0, acc[1]);   acc[1]  = fmaf(bhi(b0.x), ex1, acc[1]);
        acc[2]  = fmaf(blo(a0.y), ex0, acc[2]);   acc[2]  = fmaf(blo(b0.y), ex1, acc[2]);
        acc[3]  = fmaf(bhi(a0.y), ex0, acc[3]);   acc[3]  = fmaf(bhi(b0.y), ex1, acc[3]);
        acc[4]  = fmaf(blo(a0.z), ex0, acc[4]);   acc[4]  = fmaf(blo(b0.z), ex1, acc[4]);
        acc[5]  = fmaf(bhi(a0.z), ex0, acc[5]);   acc[5]  = fmaf(bhi(b0.z), ex1, acc[5]);
        acc[6]  = fmaf(blo(a0.w), ex0, acc[6]);   acc[6]  = fmaf(blo(b0.w), ex1, acc[6]);
        acc[7]  = fmaf(bhi(a0.w), ex0, acc[7]);   acc[7]  = fmaf(bhi(b0.w), ex1, acc[7]);
        acc[8]  = fmaf(blo(a1.x), ex0, acc[8]);   acc[8]  = fmaf(blo(b1v.x), ex1, acc[8]);
        acc[9]  = fmaf(bhi(a1.x), ex0, acc[9]);   acc[9]  = fmaf(bhi(b1v.x), ex1, acc[9]);
        acc[10] = fmaf(blo(a1.y), ex0, acc[10]);  acc[10] = fmaf(blo(b1v.y), ex1, acc[10]);
        acc[11] = fmaf(bhi(a1.y), ex0, acc[11]);  acc[11] = fmaf(bhi(b1v.y), ex1, acc[11]);
        acc[12] = fmaf(blo(a1.z), ex0, acc[12]);  acc[12] = fmaf(blo(b1v.z), ex1, acc[12]);
        acc[13] = fmaf(bhi(a1.z), ex0, acc[13]);  acc[13] = fmaf(bhi(b1v.z), ex1, acc[13]);
        acc[14] = fmaf(blo(a1.w), ex0, acc[14]);  acc[14] = fmaf(blo(b1v.w), ex1, acc[14]);
        acc[15] = fmaf(bhi(a1.w), ex0, acc[15]);  acc[15] = fmaf(bhi(b1v.w), ex1, acc[15]);
    }
    if (i < end) {
        int s = csr_src[i];
        float ex = __expf(leaky(el[s * 4 + h] + er_h));
        const uint4* p = (const uint4*)(feat1 + (size_t)s * 256 + l16 * 16);
        uint4 u0 = p[0], u1 = p[1];
        denom += ex;
        acc[0]  = fmaf(blo(u0.x), ex, acc[0]);
        acc[1]  = fmaf(bhi(u0.x), ex, acc[1]);
        acc[2]  = fmaf(blo(u0.y), ex, acc[2]);
        acc[3]  = fmaf(bhi(u0.y), ex, acc[3]);
        acc[4]  = fmaf(blo(u0.z), ex, acc[4]);
        acc[5]  = fmaf(bhi(u0.z), ex, acc[5]);
        acc[6]  = fmaf(blo(u0.w), ex, acc[6]);
        acc[7]  = fmaf(bhi(u0.w), ex, acc[7]);
        acc[8]  = fmaf(blo(u1.x), ex, acc[8]);
        acc[9]  = fmaf(bhi(u1.x), ex, acc[9]);
        acc[10] = fmaf(blo(u1.y), ex, acc[10]);
        acc[11] = fmaf(bhi(u1.y), ex, acc[11]);
        acc[12] = fmaf(blo(u1.z), ex, acc[12]);
        acc[13] = fmaf(bhi(u1.z), ex, acc[13]);
        acc[14] = fmaf(blo(u1.w), ex, acc[14]);
        acc[15] = fmaf(bhi(u1.w), ex, acc[15]);
    }
#pragma unroll
    for (int j = 0; j < 16; ++j) {
        acc[j] += __shfl_xor(acc[j], 16);
        acc[j] += __shfl_xor(acc[j], 32);
    }
    denom += __shfl_xor(denom, 16);
    denom += __shfl_xor(denom, 32);

    if (q == 0) {
        float inv = (end > start) ? 1.f / denom : 0.f;
        float o[16];
#pragma unroll
        for (int j = 0; j < 16; j += 4) {
            float4 b4 = *(const float4*)&b1[l16 * 16 + j];
            o[j + 0] = fmaf(acc[j + 0], inv, b4.x);
            o[j + 1] = fmaf(acc[j + 1], inv, b4.y);
            o[j + 2] = fmaf(acc[j + 2], inv, b4.z);
            o[j + 3] = fmaf(acc[j + 3], inv, b4.w);
        }
#pragma unroll
        for (int j = 0; j < 16; ++j) o[j] = o[j] > 0.f ? o[j] : __expf(o[j]) - 1.f;
        uint4 pa, pb;
        pa.x = pack2(o[0], o[1]);   pa.y = pack2(o[2], o[3]);
        pa.z = pack2(o[4], o[5]);   pa.w = pack2(o[6], o[7]);
        pb.x = pack2(o[8], o[9]);   pb.y = pack2(o[10], o[11]);
        pb.z = pack2(o[12], o[13]); pb.w = pack2(o[14], o[15]);
        uint4* dstp = (uint4*)(h1b + (size_t)n * 256 + l16 * 16);
        dstp[0] = pa;
        dstp[1] = pb;
    }
}

// ---------------- GEMM2 (bf16 MFMA, no LDS) + fused el2/er2 ----------------
__global__ __launch_bounds__(256) void gemm2_mfma_kernel(
        const unsigned short* __restrict__ h1b, const unsigned short* __restrict__ W2T,
        const float* __restrict__ al2, const float* __restrict__ ar2,
        float* __restrict__ feat2, float* __restrict__ el2, float* __restrict__ er2) {
    int wave = threadIdx.x >> 6, lane = threadIdx.x & 63;
    int l16 = lane & 15, quad = lane >> 4;
    int row0 = (blockIdx.x * 4 + wave) * 16;
    if (row0 >= N_NODES) return;
    floatx4 acc = (floatx4){0.f, 0.f, 0.f, 0.f};
    const unsigned short* arow = h1b + (size_t)(row0 + l16) * 256 + quad * 8;
    const unsigned short* brow = W2T + (size_t)l16 * 256 + quad * 8;
#pragma unroll
    for (int k0 = 0; k0 < 256; k0 += 32) {
        short8 a = *(const short8*)(arow + k0);
        short8 b = *(const short8*)(brow + k0);
        acc = __builtin_amdgcn_mfma_f32_16x16x32_bf16(a, b, acc, 0, 0, 0);
    }
    float a2 = al2[l16], r2 = ar2[l16];
#pragma unroll
    for (int r = 0; r < 4; ++r) {
        int row = row0 + quad * 4 + r;
        float v = acc[r];
        feat2[row * 16 + l16] = v;
        float pl = v * a2, pr = v * r2;
#pragma unroll
        for (int off = 1; off < 16; off <<= 1) {
            pl += __shfl_xor(pl, off);
            pr += __shfl_xor(pr, off);
        }
        if (l16 == 0) {
            el2[row] = pl;
            er2[row] = pr;
        }
    }
}

// ---------------- layer-2 aggregation + log_softmax, 2x unroll ----------------
__global__ void agg2_kernel(const float* __restrict__ feat2, const float* __restrict__ el2,
                            const float* __restrict__ er2, const int* __restrict__ row_ptr,
                            const int* __restrict__ csr_src, const float* __restrict__ b2,
                            float* __restrict__ out) {
    int wave = threadIdx.x >> 6, lane = threadIdx.x & 63;
    int n = blockIdx.x * 4 + wave;
    if (n >= N_NODES) return;
    int start = row_ptr[n], end = row_ptr[n + 1];
    float ern = er2[n];
    int eo = lane >> 4, c = lane & 15;
    float acc = 0.f, denom = 0.f;
    int i = start + eo;
    for (; i + 4 < end; i += 8) {
        int s0 = csr_src[i], s1 = csr_src[i + 4];
        float ex0 = __expf(leaky(el2[s0] + ern));
        float ex1 = __expf(leaky(el2[s1] + ern));
        float f0 = feat2[s0 * 16 + c], f1 = feat2[s1 * 16 + c];
        denom += ex0 + ex1;
        acc = fmaf(f0, ex0, acc);
        acc = fmaf(f1, ex1, acc);
    }
    if (i < end) {
        int s = csr_src[i];
        float ex = __expf(leaky(el2[s] + ern));
        denom += ex;
        acc = fmaf(feat2[s * 16 + c], ex, acc);
    }
    acc += __shfl_xor(acc, 16);
    acc += __shfl_xor(acc, 32);
    denom += __shfl_xor(denom, 16);
    denom += __shfl_xor(denom, 32);
    float v = ((end > start) ? acc / denom : 0.f) + b2[c];
    float mx = v;
#pragma unroll
    for (int off = 1; off < 16; off <<= 1) mx = fmaxf(mx, __shfl_xor(mx, off));
    float ex2 = __expf(v - mx);
    float s2 = ex2;
#pragma unroll
    for (int off = 1; off < 16; off <<= 1) s2 += __shfl_xor(s2, off);
    float res = v - mx - logf(s2);
    if (lane < 16) out[n * 16 + lane] = res;
}

// ---------------- launch ----------------
extern "C" void kernel_launch(void* const* d_in, const int* in_sizes, int n_in,
                              void* d_out, int out_size, void* d_ws, size_t ws_size,
                              hipStream_t stream) {
    const float* x   = (const float*)d_in[0];
    const int*   src = (const int*)d_in[1];
    const int*   dst = (const int*)d_in[2];
    const float* W1  = (const float*)d_in[3];
    const float* al1 = (const float*)d_in[4];
    const float* ar1 = (const float*)d_in[5];
    const float* b1  = (const float*)d_in[6];
    const float* W2  = (const float*)d_in[7];
    const float* al2 = (const float*)d_in[8];
    const float* ar2 = (const float*)d_in[9];
    const float* b2  = (const float*)d_in[10];
    float* out = (float*)d_out;

    char* ws = (char*)d_ws;
    size_t off = 0;
    auto alloc = [&](size_t bytes) -> void* {
        void* p = ws + off;
        off += (bytes + 255) & ~(size_t)255;
        return p;
    };
    unsigned short* W1E   = (unsigned short*)alloc((size_t)272 * 256 * 2);
    unsigned short* W2T   = (unsigned short*)alloc((size_t)16 * 256 * 2);
    unsigned short* feat1 = (unsigned short*)alloc((size_t)N_NODES * 256 * 2);
    unsigned short* h1b   = (unsigned short*)alloc((size_t)N_NODES * 256 * 2);
    float* feat2   = (float*)alloc((size_t)N_NODES * 16 * 4);
    float* el1     = (float*)alloc((size_t)N_NODES * 4 * 4);
    float* er1     = (float*)alloc((size_t)N_NODES * 4 * 4);
    float* el2     = (float*)alloc((size_t)N_NODES * 4);
    float* er2     = (float*)alloc((size_t)N_NODES * 4);
    int*   cnt     = (int*)alloc((size_t)N_NODES * 4);
    int*   fill    = (int*)alloc((size_t)N_NODES * 4);
    int*   row_ptr = (int*)alloc((size_t)NP1 * 4);
    int*   partial = (int*)alloc((size_t)NP1 * 4);
    int*   bsum    = (int*)alloc((size_t)64 * 4);
    int*   csr_src = (int*)alloc((size_t)N_EDGES * 4);

    hipMemsetAsync(cnt, 0, (size_t)N_NODES * 4, stream);

    dim3 b256(256);
    prep_kernel<<<257, b256, 0, stream>>>(W1, W2, al1, ar1, W1E, W2T);
    hist_kernel<<<(N_EDGES / 4 + 255) / 256, b256, 0, stream>>>(dst, cnt);
    scan1_kernel<<<49, b256, 0, stream>>>(cnt, partial, bsum);
    scan3_kernel<<<(NP1 + 255) / 256, b256, 0, stream>>>(partial, bsum, row_ptr, fill);
    scatter_kernel<<<(N_EDGES / 4 + 255) / 256, b256, 0, stream>>>(src, dst, fill, csr_src);

    gemm1_mfma_kernel<<<(N_NODES + 127) / 128, b256, 0, stream>>>(x, W1E, feat1, el1, er1);
    agg1_kernel<<<(N_NODES + 3) / 4, b256, 0, stream>>>(feat1, el1, er1, row_ptr, csr_src, b1, h1b);

    gemm2_mfma_kernel<<<(N_NODES + 63) / 64, b256, 0, stream>>>(h1b, W2T, al2, ar2, feat2, el2, er2);
    agg2_kernel<<<(N_NODES + 3) / 4, b256, 0, stream>>>(feat2, el2, er2, row_ptr, csr_src, b2, out);
}